// Round 1
// baseline (631.172 us; speedup 1.0000x reference)
//
#include <hip/hip_runtime.h>

#define N_NODES 100000
#define N_EDGES 1600000
#define N_TOT   1700000   // edges + self-loops
#define D_IN    128
#define D_H     8
#define N_MASK  10000

__device__ __forceinline__ float lrelu(float v, float s){ return v > 0.f ? v : s*v; }

__device__ __forceinline__ float wave_sum(float v){
#pragma unroll
  for (int o = 32; o > 0; o >>= 1) v += __shfl_xor(v, o, 64);
  return v;
}

// mask_slot[node] = slot index (0..N_MASK-1) or -1
__global__ void k_mask_slot(const int* __restrict__ mask_nodes, int* __restrict__ mask_slot){
  int i = blockIdx.x*blockDim.x + threadIdx.x;
  if (i < N_MASK) mask_slot[mask_nodes[i]] = i;
}

// encoder node stage: h1 = use_x @ W^T, as1/ad1 = h1·a_src / h1·a_dst (wave per node)
__global__ void k_enc_node(const float* __restrict__ x, const float* __restrict__ token,
                           const float* __restrict__ W, const float* __restrict__ a_src,
                           const float* __restrict__ a_dst, const int* __restrict__ mask_slot,
                           float* __restrict__ h1, float* __restrict__ as1, float* __restrict__ ad1){
  __shared__ float Ws[D_H*D_IN];
  for (int t = threadIdx.x; t < D_H*D_IN; t += blockDim.x) Ws[t] = W[t];
  __syncthreads();
  int wid  = (blockIdx.x*blockDim.x + threadIdx.x) >> 6;
  int lane = threadIdx.x & 63;
  if (wid >= N_NODES) return;
  const float* row = (mask_slot[wid] >= 0) ? token : (x + (size_t)wid*D_IN);
  float2 xv = *(const float2*)(row + 2*lane);
  float p[D_H];
#pragma unroll
  for (int j = 0; j < D_H; ++j)
    p[j] = xv.x*Ws[j*D_IN + 2*lane] + xv.y*Ws[j*D_IN + 2*lane + 1];
#pragma unroll
  for (int j = 0; j < D_H; ++j) p[j] = wave_sum(p[j]);
  if (lane == 0){
    float as = 0.f, ad = 0.f;
#pragma unroll
    for (int j = 0; j < D_H; ++j){
      h1[(size_t)wid*D_H + j] = p[j];
      as += p[j]*a_src[j];
      ad += p[j]*a_dst[j];
    }
    as1[wid] = as; ad1[wid] = ad;
  }
}

// encoder edge pass A: denom1[d] += exp(lrelu(as1[s]+ad1[d], 0.2))
__global__ void k_enc_edgeA(const int* __restrict__ ei, const float* __restrict__ as1,
                            const float* __restrict__ ad1, float* __restrict__ denom1){
  int t = blockIdx.x*blockDim.x + threadIdx.x;
  if (t >= N_TOT) return;
  int s, d;
  if (t < N_EDGES){ s = ei[t]; d = ei[N_EDGES + t]; } else { s = t - N_EDGES; d = s; }
  float ee = lrelu(as1[s] + ad1[d], 0.2f);
  atomicAdd(&denom1[d], __expf(ee));
}

// encoder edge pass B: acc1[d][j] += (exp(e)/denom1[d]) * h1[s][j]   (thread per edge*8)
__global__ void k_enc_edgeB(const int* __restrict__ ei, const float* __restrict__ as1,
                            const float* __restrict__ ad1, const float* __restrict__ denom1,
                            const float* __restrict__ h1, float* __restrict__ acc1){
  long long g = (long long)blockIdx.x*blockDim.x + threadIdx.x;
  if (g >= (long long)N_TOT*D_H) return;
  int t = (int)(g >> 3), j = (int)(g & 7);
  int s, d;
  if (t < N_EDGES){ s = ei[t]; d = ei[N_EDGES + t]; } else { s = t - N_EDGES; d = s; }
  float ee = lrelu(as1[s] + ad1[d], 0.2f);
  float w  = __expf(ee) / denom1[d];
  atomicAdd(&acc1[(size_t)d*D_H + j], w * h1[(size_t)s*D_H + j]);
}

// encoder finish: enc_rep = lrelu(acc1+b, .01) -> d_out; rep = enc_rep @ e2d_W^T, masked rows 0
__global__ void k_enc_fin(const float* __restrict__ acc1, const float* __restrict__ enc_b,
                          const float* __restrict__ e2dW, const int* __restrict__ mask_slot,
                          float* __restrict__ out_rep, float* __restrict__ rep){
  int i = blockIdx.x*blockDim.x + threadIdx.x;
  if (i >= N_NODES) return;
  float er[D_H];
#pragma unroll
  for (int j = 0; j < D_H; ++j){
    er[j] = lrelu(acc1[(size_t)i*D_H + j] + enc_b[j], 0.01f);
    out_rep[(size_t)i*D_H + j] = er[j];
  }
  bool masked = mask_slot[i] >= 0;
#pragma unroll
  for (int k = 0; k < D_H; ++k){
    float v = 0.f;
#pragma unroll
    for (int j = 0; j < D_H; ++j) v += er[j]*e2dW[k*D_H + j];
    rep[(size_t)i*D_H + k] = masked ? 0.f : v;
  }
}

// decoder node stage: h2 = rep @ dec_W^T (N x 128), as2/ad2 dots (wave per node)
__global__ void k_dec_node(const float* __restrict__ rep, const float* __restrict__ Wd,
                           const float* __restrict__ a_src, const float* __restrict__ a_dst,
                           float* __restrict__ h2, float* __restrict__ as2, float* __restrict__ ad2){
  __shared__ float Ws[D_IN*D_H];
  for (int t = threadIdx.x; t < D_IN*D_H; t += blockDim.x) Ws[t] = Wd[t];
  __syncthreads();
  int wid  = (blockIdx.x*blockDim.x + threadIdx.x) >> 6;
  int lane = threadIdx.x & 63;
  if (wid >= N_NODES) return;
  float r[D_H];
#pragma unroll
  for (int k = 0; k < D_H; ++k) r[k] = rep[(size_t)wid*D_H + k];
  int j0 = 2*lane, j1 = j0 + 1;
  float h20 = 0.f, h21 = 0.f;
#pragma unroll
  for (int k = 0; k < D_H; ++k){ h20 += r[k]*Ws[j0*D_H + k]; h21 += r[k]*Ws[j1*D_H + k]; }
  *(float2*)(h2 + (size_t)wid*D_IN + j0) = make_float2(h20, h21);
  float pas = h20*a_src[j0] + h21*a_src[j1];
  float pad = h20*a_dst[j0] + h21*a_dst[j1];
  pas = wave_sum(pas); pad = wave_sum(pad);
  if (lane == 0){ as2[wid] = pas; ad2[wid] = pad; }
}

// decoder edge pass A: only masked dst. denom2[slot] += exp(...)
__global__ void k_dec_edgeA(const int* __restrict__ ei, const int* __restrict__ mask_slot,
                            const float* __restrict__ as2, const float* __restrict__ ad2,
                            float* __restrict__ denom2){
  int t = blockIdx.x*blockDim.x + threadIdx.x;
  if (t >= N_TOT) return;
  int s, d;
  if (t < N_EDGES){ s = ei[t]; d = ei[N_EDGES + t]; } else { s = t - N_EDGES; d = s; }
  int slot = mask_slot[d];
  if (slot < 0) return;
  float ee = lrelu(as2[s] + ad2[d], 0.2f);
  atomicAdd(&denom2[slot], __expf(ee));
}

// decoder edge pass B: wave per edge, 128 features, only masked dst
__global__ void k_dec_edgeB(const int* __restrict__ ei, const int* __restrict__ mask_slot,
                            const float* __restrict__ as2, const float* __restrict__ ad2,
                            const float* __restrict__ denom2, const float* __restrict__ h2,
                            float* __restrict__ acc2){
  int wid  = (blockIdx.x*blockDim.x + threadIdx.x) >> 6;
  int lane = threadIdx.x & 63;
  if (wid >= N_TOT) return;
  int s, d;
  if (wid < N_EDGES){ s = ei[wid]; d = ei[N_EDGES + wid]; } else { s = wid - N_EDGES; d = s; }
  int slot = mask_slot[d];
  if (slot < 0) return;
  float ee = lrelu(as2[s] + ad2[d], 0.2f);
  float w  = __expf(ee) / denom2[slot];
  atomicAdd(&acc2[(size_t)slot*D_IN + lane],      w * h2[(size_t)s*D_IN + lane]);
  atomicAdd(&acc2[(size_t)slot*D_IN + lane + 64], w * h2[(size_t)s*D_IN + lane + 64]);
}

// loss: wave per masked slot; cos(recon[mask], x[mask]) summed atomically
__global__ void k_loss(const float* __restrict__ acc2, const float* __restrict__ dec_b,
                       const int* __restrict__ mask_nodes, const float* __restrict__ x,
                       float* __restrict__ cos_sum){
  int wid  = (blockIdx.x*blockDim.x + threadIdx.x) >> 6;
  int lane = threadIdx.x & 63;
  if (wid >= N_MASK) return;
  int node = mask_nodes[wid];
  float dot = 0.f, na = 0.f, nb = 0.f;
#pragma unroll
  for (int h = 0; h < 2; ++h){
    int f = lane + 64*h;
    float r  = lrelu(acc2[(size_t)wid*D_IN + f] + dec_b[f], 0.01f);
    float xi = x[(size_t)node*D_IN + f];
    dot += r*xi; na += r*r; nb += xi*xi;
  }
  dot = wave_sum(dot); na = wave_sum(na); nb = wave_sum(nb);
  if (lane == 0){
    float den = fmaxf(sqrtf(na), 1e-8f) * fmaxf(sqrtf(nb), 1e-8f);
    atomicAdd(cos_sum, dot/den);
  }
}

__global__ void k_fin(const float* __restrict__ cos_sum, float* __restrict__ out){
  out[0] = 1.0f - cos_sum[0] / (float)N_MASK;
}

extern "C" void kernel_launch(void* const* d_in, const int* in_sizes, int n_in,
                              void* d_out, int out_size, void* d_ws, size_t ws_size,
                              hipStream_t stream){
  const float* x          = (const float*)d_in[0];
  const int*   ei         = (const int*)  d_in[1];
  const int*   mask_nodes = (const int*)  d_in[2];
  const float* token      = (const float*)d_in[3];
  const float* enc_W      = (const float*)d_in[4];
  const float* enc_as     = (const float*)d_in[5];
  const float* enc_ad     = (const float*)d_in[6];
  const float* enc_b      = (const float*)d_in[7];
  const float* e2d_W      = (const float*)d_in[8];
  const float* dec_W      = (const float*)d_in[9];
  const float* dec_as     = (const float*)d_in[10];
  const float* dec_ad     = (const float*)d_in[11];
  const float* dec_b      = (const float*)d_in[12];
  float* out = (float*)d_out;

  char* w = (char*)d_ws;
  size_t off = 0;
  auto alloc = [&](size_t bytes)->char*{ char* p = w + off; off += (bytes + 255)/256*256; return p; };
  // zero-init region (one memset)
  float* denom1  = (float*)alloc((size_t)N_NODES*4);
  float* acc1    = (float*)alloc((size_t)N_NODES*D_H*4);
  float* denom2  = (float*)alloc((size_t)N_MASK*4);
  float* acc2    = (float*)alloc((size_t)N_MASK*D_IN*4);
  float* cos_sum = (float*)alloc(4);
  size_t zero_bytes = off;
  int*   mask_slot = (int*)  alloc((size_t)N_NODES*4);
  float* h1  = (float*)alloc((size_t)N_NODES*D_H*4);
  float* as1 = (float*)alloc((size_t)N_NODES*4);
  float* ad1 = (float*)alloc((size_t)N_NODES*4);
  float* rep = (float*)alloc((size_t)N_NODES*D_H*4);
  float* h2  = (float*)alloc((size_t)N_NODES*D_IN*4);
  float* as2 = (float*)alloc((size_t)N_NODES*4);
  float* ad2 = (float*)alloc((size_t)N_NODES*4);

  hipMemsetAsync(d_ws, 0, zero_bytes, stream);
  hipMemsetAsync(mask_slot, 0xFF, (size_t)N_NODES*4, stream);

  k_mask_slot<<<(N_MASK + 255)/256, 256, 0, stream>>>(mask_nodes, mask_slot);
  k_enc_node <<<(N_NODES*64 + 255)/256, 256, 0, stream>>>(x, token, enc_W, enc_as, enc_ad,
                                                          mask_slot, h1, as1, ad1);
  k_enc_edgeA<<<(N_TOT + 255)/256, 256, 0, stream>>>(ei, as1, ad1, denom1);
  k_enc_edgeB<<<(int)(((long long)N_TOT*8 + 255)/256), 256, 0, stream>>>(ei, as1, ad1, denom1, h1, acc1);
  k_enc_fin  <<<(N_NODES + 255)/256, 256, 0, stream>>>(acc1, enc_b, e2d_W, mask_slot, out + 1, rep);
  k_dec_node <<<(N_NODES*64 + 255)/256, 256, 0, stream>>>(rep, dec_W, dec_as, dec_ad, h2, as2, ad2);
  k_dec_edgeA<<<(N_TOT + 255)/256, 256, 0, stream>>>(ei, mask_slot, as2, ad2, denom2);
  k_dec_edgeB<<<(int)(((long long)N_TOT*64 + 255)/256), 256, 0, stream>>>(ei, mask_slot, as2, ad2,
                                                                          denom2, h2, acc2);
  k_loss     <<<(N_MASK*64 + 255)/256, 256, 0, stream>>>(acc2, dec_b, mask_nodes, x, cos_sum);
  k_fin      <<<1, 1, 0, stream>>>(cos_sum, out);
}